// Round 2
// baseline (951.300 us; speedup 1.0000x reference)
//
#include <hip/hip_runtime.h>

#define NROWS 262144
#define KDIM  512
#define ODIM  128

typedef __attribute__((ext_vector_type(8))) __bf16 bf16x8;
typedef __attribute__((ext_vector_type(4))) __bf16 bf16x4;
typedef __attribute__((ext_vector_type(4))) float  f32x4;

// ---- workspace layout (bytes) ----
// [0      , 131072): Wh  bf16[128*512]
// [131072 , 262144): Wl  bf16[128*512]
// [262144 , 278528): partials double[2048]
// [278528 , 279552): counts  int[256]

// ---------------- W pre-convert: fp32 -> (hi, lo) bf16 ----------------
__global__ __launch_bounds__(256) void convert_w_kernel(
    const float* __restrict__ W, __bf16* __restrict__ Wh, __bf16* __restrict__ Wl) {
  int gid = blockIdx.x * 256 + threadIdx.x;  // 16384 threads, 1 float4 each
  float4 w = ((const float4*)W)[gid];
  float wf[4] = {w.x, w.y, w.z, w.w};
  bf16x4 h, l;
#pragma unroll
  for (int e = 0; e < 4; ++e) {
    __bf16 hh = (__bf16)wf[e];
    h[e] = hh;
    l[e] = (__bf16)(wf[e] - (float)hh);  // residual is exact in fp32, then RNE
  }
  *(bf16x4*)(Wh + (size_t)gid * 4) = h;
  *(bf16x4*)(Wl + (size_t)gid * 4) = l;
}

// ---------------- GEMM: out = x @ W^T + b, split-bf16 3-MFMA ----------------
// block = 256 thr (4 waves); each wave owns 32 rows x 128 cols (2 row-subtiles
// of 16 so each B fragment pair feeds 6 MFMAs -> halves L2 B-traffic vs 16-row).
// A-frag (16x16x32): lane holds A[m=lane&15][k = 8*(lane>>4)+e], e=0..7 ->
// 8 consecutive fp32 of one x row (2x dwordx4), split-converted to hi/lo bf16.
// B-frag: lane holds B[k=8*(lane>>4)+e][n=lane&15] = W[n][k] -> 8 consecutive
// bf16 of one W row (1x dwordx4). (contiguous-k per lane: m92/m97 ref-checked)
__global__ __launch_bounds__(256, 2) void gemm_kernel(
    const float* __restrict__ x, const __bf16* __restrict__ Wh,
    const __bf16* __restrict__ Wl, const float* __restrict__ bias,
    float* __restrict__ out, double* __restrict__ partials) {
  const int lane = threadIdx.x & 63;
  const int wid  = threadIdx.x >> 6;
  const int ncol = lane & 15;
  const int kg   = lane >> 4;  // k-subgroup 0..3 (8 elems each)

  const int row0 = blockIdx.x * 128 + wid * 32 + ncol;  // A-load row, subtile 0
  const float* xrow0 = x + (size_t)row0 * KDIM + kg * 8;
  const float* xrow1 = xrow0 + (size_t)16 * KDIM;

  f32x4 acc[2][8];
#pragma unroll
  for (int rs = 0; rs < 2; ++rs)
#pragma unroll
    for (int ct = 0; ct < 8; ++ct) acc[rs][ct] = (f32x4){0.f, 0.f, 0.f, 0.f};

  float a_cur[2][8];
#pragma unroll
  for (int rs = 0; rs < 2; ++rs) {
    const float4* p = (const float4*)(rs ? xrow1 : xrow0);
    float4 v0 = p[0], v1 = p[1];
    a_cur[rs][0] = v0.x; a_cur[rs][1] = v0.y; a_cur[rs][2] = v0.z; a_cur[rs][3] = v0.w;
    a_cur[rs][4] = v1.x; a_cur[rs][5] = v1.y; a_cur[rs][6] = v1.z; a_cur[rs][7] = v1.w;
  }

  for (int kc = 0; kc < KDIM / 32; ++kc) {
    const int k0 = kc * 32;
    // prefetch next K-chunk of A (clamped on last iter; redundant re-load)
    float a_nxt[2][8];
    {
      const int kn = (kc < 15) ? (k0 + 32) : k0;
#pragma unroll
      for (int rs = 0; rs < 2; ++rs) {
        const float4* p = (const float4*)((rs ? xrow1 : xrow0) + kn);
        float4 v0 = p[0], v1 = p[1];
        a_nxt[rs][0] = v0.x; a_nxt[rs][1] = v0.y; a_nxt[rs][2] = v0.z; a_nxt[rs][3] = v0.w;
        a_nxt[rs][4] = v1.x; a_nxt[rs][5] = v1.y; a_nxt[rs][6] = v1.z; a_nxt[rs][7] = v1.w;
      }
    }
    // split-convert A to hi/lo bf16
    bf16x8 ah[2], al[2];
#pragma unroll
    for (int rs = 0; rs < 2; ++rs)
#pragma unroll
      for (int e = 0; e < 8; ++e) {
        float f = a_cur[rs][e];
        __bf16 h = (__bf16)f;
        ah[rs][e] = h;
        al[rs][e] = (__bf16)(f - (float)h);
      }
    const int kb = k0 + kg * 8;
#pragma unroll
    for (int ct = 0; ct < 8; ++ct) {
      const size_t boff = (size_t)(ct * 16 + ncol) * KDIM + kb;
      bf16x8 bh = *(const bf16x8*)(Wh + boff);
      bf16x8 bl = *(const bf16x8*)(Wl + boff);
#pragma unroll
      for (int rs = 0; rs < 2; ++rs) {
        acc[rs][ct] = __builtin_amdgcn_mfma_f32_16x16x32_bf16(ah[rs], bh, acc[rs][ct], 0, 0, 0);
        acc[rs][ct] = __builtin_amdgcn_mfma_f32_16x16x32_bf16(al[rs], bh, acc[rs][ct], 0, 0, 0);
        acc[rs][ct] = __builtin_amdgcn_mfma_f32_16x16x32_bf16(ah[rs], bl, acc[rs][ct], 0, 0, 0);
      }
    }
#pragma unroll
    for (int rs = 0; rs < 2; ++rs)
#pragma unroll
      for (int e = 0; e < 8; ++e) a_cur[rs][e] = a_nxt[rs][e];
  }

  // epilogue: + bias, write out, side-reduce tile sum (for threshold)
  // C/D layout (m89): col = lane&15, row = (lane>>4)*4 + reg
  double lsum = 0.0;
#pragma unroll
  for (int rs = 0; rs < 2; ++rs) {
    const int orow0 = blockIdx.x * 128 + wid * 32 + rs * 16 + kg * 4;
#pragma unroll
    for (int ct = 0; ct < 8; ++ct) {
      float bv = bias[ct * 16 + ncol];
#pragma unroll
      for (int r = 0; r < 4; ++r) {
        float v = acc[rs][ct][r] + bv;
        out[(size_t)(orow0 + r) * ODIM + ct * 16 + ncol] = v;
        lsum += (double)v;
      }
    }
  }
#pragma unroll
  for (int off = 32; off; off >>= 1) lsum += __shfl_xor(lsum, off);
  __shared__ double wpart[4];
  if (lane == 0) wpart[wid] = lsum;
  __syncthreads();
  if (threadIdx.x == 0)
    partials[blockIdx.x] = wpart[0] + wpart[1] + wpart[2] + wpart[3];
}

// ---------------- threshold (redundant per block) + count + fill -1 ----------------
__device__ inline float compute_threshold(const double* __restrict__ partials,
                                          double* __restrict__ red) {
  double s = 0.0;
  for (int j = threadIdx.x; j < 2048; j += 256) s += partials[j];
  red[threadIdx.x] = s;
  __syncthreads();
  for (int st = 128; st; st >>= 1) {
    if ((int)threadIdx.x < st) red[threadIdx.x] += red[threadIdx.x + st];
    __syncthreads();
  }
  return (float)(red[0] / (double)NROWS);
}

__global__ __launch_bounds__(256) void count_kernel(
    const float* __restrict__ mask, const double* __restrict__ partials,
    int* __restrict__ counts, float* __restrict__ idx_out) {
  __shared__ double red[256];
  float thr = compute_threshold(partials, red);

  int base = blockIdx.x * 1024 + threadIdx.x * 4;
  float4 m = *(const float4*)(mask + base);
  int c = (m.x > thr) + (m.y > thr) + (m.z > thr) + (m.w > thr);
  *(float4*)(idx_out + base) = (float4){-1.f, -1.f, -1.f, -1.f};

  __shared__ int ired[256];
  ired[threadIdx.x] = c;
  __syncthreads();
  for (int st = 128; st; st >>= 1) {
    if ((int)threadIdx.x < st) ired[threadIdx.x] += ired[threadIdx.x + st];
    __syncthreads();
  }
  if (threadIdx.x == 0) counts[blockIdx.x] = ired[0];
}

// ---------------- ordered scatter ----------------
__global__ __launch_bounds__(256) void scatter_kernel(
    const float* __restrict__ mask, const double* __restrict__ partials,
    const int* __restrict__ counts, float* __restrict__ idx_out) {
  __shared__ double red[256];
  float thr = compute_threshold(partials, red);  // bit-identical to count_kernel

  __shared__ int blockPrefix;
  if (threadIdx.x == 0) {
    int p = 0;
    for (int j = 0; j < (int)blockIdx.x; ++j) p += counts[j];
    blockPrefix = p;
  }

  int base = blockIdx.x * 1024 + threadIdx.x * 4;
  float4 m = *(const float4*)(mask + base);
  int p0 = m.x > thr, p1 = m.y > thr, p2 = m.z > thr, p3 = m.w > thr;
  int tc = p0 + p1 + p2 + p3;

  int lane = threadIdx.x & 63, wv = threadIdx.x >> 6;
  int incl = tc;
#pragma unroll
  for (int off = 1; off < 64; off <<= 1) {
    int v = __shfl_up(incl, off);
    if (lane >= off) incl += v;
  }
  __shared__ int wsum[4];
  if (lane == 63) wsum[wv] = incl;
  __syncthreads();
  int wbase = 0;
  for (int w = 0; w < wv; ++w) wbase += wsum[w];

  int pos = blockPrefix + wbase + (incl - tc);
  if (p0) idx_out[pos++] = (float)(base + 0);
  if (p1) idx_out[pos++] = (float)(base + 1);
  if (p2) idx_out[pos++] = (float)(base + 2);
  if (p3) idx_out[pos++] = (float)(base + 3);
}

extern "C" void kernel_launch(void* const* d_in, const int* in_sizes, int n_in,
                              void* d_out, int out_size, void* d_ws, size_t ws_size,
                              hipStream_t stream) {
  const float* x    = (const float*)d_in[0];
  const float* mask = (const float*)d_in[1];
  const float* W    = (const float*)d_in[2];
  const float* bias = (const float*)d_in[3];

  float* out     = (float*)d_out;
  float* idx_out = out + (size_t)NROWS * ODIM;

  char*   ws       = (char*)d_ws;
  __bf16* Wh       = (__bf16*)(ws);
  __bf16* Wl       = (__bf16*)(ws + 131072);
  double* partials = (double*)(ws + 262144);
  int*    counts   = (int*)(ws + 278528);

  convert_w_kernel<<<64, 256, 0, stream>>>(W, Wh, Wl);
  gemm_kernel<<<2048, 256, 0, stream>>>(x, Wh, Wl, bias, out, partials);
  count_kernel<<<256, 256, 0, stream>>>(mask, partials, counts, idx_out);
  scatter_kernel<<<256, 256, 0, stream>>>(mask, partials, counts, idx_out);
}

// Round 5
// 752.586 us; speedup vs baseline: 1.2640x; 1.2640x over previous
//
#include <hip/hip_runtime.h>

#define NROWS 262144
#define KDIM  512
#define ODIM  128

typedef __attribute__((ext_vector_type(8))) __bf16 bf16x8;
typedef __attribute__((ext_vector_type(4))) float  f32x4;

typedef __attribute__((address_space(1))) const unsigned int* gas_u32p;
typedef __attribute__((address_space(3))) unsigned int*       las_u32p;

// ---- workspace layout (bytes) ----
// [0      , 262144): Wp  packed split-bf16 W, 16 kc-slices x 16KB.
//   slice kc holds 1024 chunks of 16B; chunk for (row r, hl, kg) at index
//   r*8 + ((hl*4+kg) ^ (r&7))  [XOR swizzle baked into GLOBAL layout so the
//   LDS staging copy is linear and ds_read_b128 is bank-conflict-free]
//   chunk data: bf16 of W[r][kc*32+kg*8 .. +8] (hl=0: hi, hl=1: residual lo)
// [262144, 278528): partials double[2048]
// [278528, 279552): counts  int[256]
// [279552, 280576): offsets int[256]

// ---------------- W pre-convert: fp32 -> packed swizzled (hi,lo) ----------------
__global__ __launch_bounds__(256) void convert_w_kernel(
    const float* __restrict__ W, char* __restrict__ WpB) {
  int gid = blockIdx.x * 256 + threadIdx.x;  // 8192 threads: kc(16) x r(128) x kg(4)
  int kg = gid & 3, r = (gid >> 2) & 127, kc = gid >> 9;
  const float4* src = (const float4*)(W + (size_t)r * KDIM + kc * 32 + kg * 8);
  float4 v0 = src[0], v1 = src[1];
  float f[8] = {v0.x, v0.y, v0.z, v0.w, v1.x, v1.y, v1.z, v1.w};
  bf16x8 h, l;
#pragma unroll
  for (int e = 0; e < 8; ++e) {
    __bf16 hh = (__bf16)f[e];
    h[e] = hh;
    l[e] = (__bf16)(f[e] - (float)hh);  // residual exact in fp32, then RNE
  }
  char* slice = WpB + (size_t)kc * 16384 + r * 128;  // r*8 chunks * 16B
  int swz = r & 7;
  *(bf16x8*)(slice + ((kg ^ swz)) * 16)       = h;
  *(bf16x8*)(slice + (((4 + kg) ^ swz)) * 16) = l;
}

// ---------------- GEMM: out = x @ W^T + b, split-bf16 3-MFMA ----------------
// R2 diagnosis: latency-bound on B-load->MFMA chain (MfmaUtil 10%, all pipes
// idle). Fix: double-buffered LDS staging of B via async global_load_lds
// (16KB/kc-slice), one barrier per K-iter; A stays as depth-1 register
// prefetch (per-lane global pattern == A-frag layout). Numerics identical
// to the R2-benched kernel (same MFMA order) -> absmax unchanged.
__global__ __launch_bounds__(256, 3) void gemm_kernel(
    const float* __restrict__ x, const char* __restrict__ WpB,
    const float* __restrict__ bias, float* __restrict__ out,
    double* __restrict__ partials) {
  const int lane = threadIdx.x & 63;
  const int wid  = threadIdx.x >> 6;
  const int ncol = lane & 15;
  const int kg   = lane >> 4;  // k-subgroup 0..3 (8 elems each)

  __shared__ __align__(16) char lds[32768];  // 2 x 16KB B-slice buffers

  const int row0 = blockIdx.x * 128 + wid * 32 + ncol;  // A rows, subtile 0
  const float* xrow0 = x + (size_t)row0 * KDIM + kg * 8;
  const float* xrow1 = xrow0 + (size_t)16 * KDIM;

  f32x4 acc[2][8];
#pragma unroll
  for (int rs = 0; rs < 2; ++rs)
#pragma unroll
    for (int ct = 0; ct < 8; ++ct) acc[rs][ct] = (f32x4){0.f, 0.f, 0.f, 0.f};

  // ---- stage slice 0 into buffer 0 (linear 16KB copy, 4 chunks/thread) ----
#pragma unroll
  for (int i = 0; i < 4; ++i) {
    const int cbase = (wid * 4 + i) * 64;  // wave-uniform chunk base
    __builtin_amdgcn_global_load_lds(
        (gas_u32p)(WpB + (size_t)(cbase + lane) * 16),
        (las_u32p)(lds + cbase * 16), 16, 0, 0);
  }

  // ---- preload A chunk 0 ----
  float a_cur[2][8];
#pragma unroll
  for (int rs = 0; rs < 2; ++rs) {
    const float4* p = (const float4*)(rs ? xrow1 : xrow0);
    float4 v0 = p[0], v1 = p[1];
    a_cur[rs][0] = v0.x; a_cur[rs][1] = v0.y; a_cur[rs][2] = v0.z; a_cur[rs][3] = v0.w;
    a_cur[rs][4] = v1.x; a_cur[rs][5] = v1.y; a_cur[rs][6] = v1.z; a_cur[rs][7] = v1.w;
  }
  __syncthreads();  // compiler emits vmcnt(0) before s_barrier -> slice 0 ready

#pragma unroll 2
  for (int kc = 0; kc < KDIM / 32; ++kc) {
    const char* cur = lds + (kc & 1) * 16384;
    // stage next slice into the other buffer (async; read next iter)
    if (kc < 15) {
      const char* gsrc = WpB + (size_t)(kc + 1) * 16384;
      char* dst = lds + ((kc + 1) & 1) * 16384;
#pragma unroll
      for (int i = 0; i < 4; ++i) {
        const int cbase = (wid * 4 + i) * 64;
        __builtin_amdgcn_global_load_lds(
            (gas_u32p)(gsrc + (size_t)(cbase + lane) * 16),
            (las_u32p)(dst + cbase * 16), 16, 0, 0);
      }
    }
    // prefetch next A chunk (regs, depth-1; clamped on last iter)
    float a_nxt[2][8];
    {
      const int kn = (kc < 15) ? (kc * 32 + 32) : kc * 32;
#pragma unroll
      for (int rs = 0; rs < 2; ++rs) {
        const float4* p = (const float4*)((rs ? xrow1 : xrow0) + kn);
        float4 v0 = p[0], v1 = p[1];
        a_nxt[rs][0] = v0.x; a_nxt[rs][1] = v0.y; a_nxt[rs][2] = v0.z; a_nxt[rs][3] = v0.w;
        a_nxt[rs][4] = v1.x; a_nxt[rs][5] = v1.y; a_nxt[rs][6] = v1.z; a_nxt[rs][7] = v1.w;
      }
    }
    // split-convert current A chunk to hi/lo bf16
    bf16x8 ah[2], al[2];
#pragma unroll
    for (int rs = 0; rs < 2; ++rs)
#pragma unroll
      for (int e = 0; e < 8; ++e) {
        float f = a_cur[rs][e];
        __bf16 h = (__bf16)f;
        ah[rs][e] = h;
        al[rs][e] = (__bf16)(f - (float)h);
      }
    // MFMA over 8 col-tiles; B frags from LDS (swizzled addr, 2-way max)
#pragma unroll
    for (int ct = 0; ct < 8; ++ct) {
      const int r   = ct * 16 + ncol;
      const int swz = r & 7;
      bf16x8 bh = *(const bf16x8*)(cur + (size_t)(r * 8 + (kg ^ swz)) * 16);
      bf16x8 bl = *(const bf16x8*)(cur + (size_t)(r * 8 + ((4 + kg) ^ swz)) * 16);
#pragma unroll
      for (int rs = 0; rs < 2; ++rs) {
        acc[rs][ct] = __builtin_amdgcn_mfma_f32_16x16x32_bf16(ah[rs], bh, acc[rs][ct], 0, 0, 0);
        acc[rs][ct] = __builtin_amdgcn_mfma_f32_16x16x32_bf16(al[rs], bh, acc[rs][ct], 0, 0, 0);
        acc[rs][ct] = __builtin_amdgcn_mfma_f32_16x16x32_bf16(ah[rs], bl, acc[rs][ct], 0, 0, 0);
      }
    }
#pragma unroll
    for (int rs = 0; rs < 2; ++rs)
#pragma unroll
      for (int e = 0; e < 8; ++e) a_cur[rs][e] = a_nxt[rs][e];
    __syncthreads();  // drains staging (vmcnt0); next buffer ready for all waves
  }

  // epilogue: + bias, write out, side-reduce tile sum (for threshold)
  // C/D layout (m89): col = lane&15, row = (lane>>4)*4 + reg
  double lsum = 0.0;
#pragma unroll
  for (int rs = 0; rs < 2; ++rs) {
    const int orow0 = blockIdx.x * 128 + wid * 32 + rs * 16 + kg * 4;
#pragma unroll
    for (int ct = 0; ct < 8; ++ct) {
      float bv = bias[ct * 16 + ncol];
#pragma unroll
      for (int r = 0; r < 4; ++r) {
        float v = acc[rs][ct][r] + bv;
        out[(size_t)(orow0 + r) * ODIM + ct * 16 + ncol] = v;
        lsum += (double)v;
      }
    }
  }
#pragma unroll
  for (int off = 32; off; off >>= 1) lsum += __shfl_xor(lsum, off);
  __shared__ double wpart[4];
  if (lane == 0) wpart[wid] = lsum;
  __syncthreads();
  if (threadIdx.x == 0)
    partials[blockIdx.x] = wpart[0] + wpart[1] + wpart[2] + wpart[3];
}

// ---------------- threshold (redundant per block) ----------------
__device__ inline float compute_threshold(const double* __restrict__ partials,
                                          double* __restrict__ red) {
  double s = 0.0;
  for (int j = threadIdx.x; j < 2048; j += 256) s += partials[j];
  red[threadIdx.x] = s;
  __syncthreads();
  for (int st = 128; st; st >>= 1) {
    if ((int)threadIdx.x < st) red[threadIdx.x] += red[threadIdx.x + st];
    __syncthreads();
  }
  return (float)(red[0] / (double)NROWS);
}

__global__ __launch_bounds__(256) void count_kernel(
    const float* __restrict__ mask, const double* __restrict__ partials,
    int* __restrict__ counts, float* __restrict__ idx_out) {
  __shared__ double red[256];
  float thr = compute_threshold(partials, red);

  int base = blockIdx.x * 1024 + threadIdx.x * 4;
  float4 m = *(const float4*)(mask + base);
  int c = (m.x > thr) + (m.y > thr) + (m.z > thr) + (m.w > thr);
  *(float4*)(idx_out + base) = (float4){-1.f, -1.f, -1.f, -1.f};

  __shared__ int ired[256];
  ired[threadIdx.x] = c;
  __syncthreads();
  for (int st = 128; st; st >>= 1) {
    if ((int)threadIdx.x < st) ired[threadIdx.x] += ired[threadIdx.x + st];
    __syncthreads();
  }
  if (threadIdx.x == 0) counts[blockIdx.x] = ired[0];
}

// ---------------- exclusive scan of block counts (1 block) ----------------
__global__ __launch_bounds__(256) void scan_kernel(
    const int* __restrict__ counts, int* __restrict__ offsets) {
  __shared__ int tmp[256];
  int tid = threadIdx.x;
  int v = counts[tid];
  tmp[tid] = v;
  __syncthreads();
#pragma unroll
  for (int st = 1; st < 256; st <<= 1) {
    int t = (tid >= st) ? tmp[tid - st] : 0;
    __syncthreads();
    tmp[tid] += t;
    __syncthreads();
  }
  offsets[tid] = tmp[tid] - v;  // exclusive prefix
}

// ---------------- ordered scatter ----------------
__global__ __launch_bounds__(256) void scatter_kernel(
    const float* __restrict__ mask, const double* __restrict__ partials,
    const int* __restrict__ offsets, float* __restrict__ idx_out) {
  __shared__ double red[256];
  float thr = compute_threshold(partials, red);  // bit-identical to count_kernel

  int base = blockIdx.x * 1024 + threadIdx.x * 4;
  float4 m = *(const float4*)(mask + base);
  int p0 = m.x > thr, p1 = m.y > thr, p2 = m.z > thr, p3 = m.w > thr;
  int tc = p0 + p1 + p2 + p3;

  int lane = threadIdx.x & 63, wv = threadIdx.x >> 6;
  int incl = tc;
#pragma unroll
  for (int off = 1; off < 64; off <<= 1) {
    int v = __shfl_up(incl, off);
    if (lane >= off) incl += v;
  }
  __shared__ int wsum[4];
  if (lane == 63) wsum[wv] = incl;
  __syncthreads();
  int wbase = 0;
  for (int w = 0; w < wv; ++w) wbase += wsum[w];

  int pos = offsets[blockIdx.x] + wbase + (incl - tc);
  if (p0) idx_out[pos++] = (float)(base + 0);
  if (p1) idx_out[pos++] = (float)(base + 1);
  if (p2) idx_out[pos++] = (float)(base + 2);
  if (p3) idx_out[pos++] = (float)(base + 3);
}

extern "C" void kernel_launch(void* const* d_in, const int* in_sizes, int n_in,
                              void* d_out, int out_size, void* d_ws, size_t ws_size,
                              hipStream_t stream) {
  const float* x    = (const float*)d_in[0];
  const float* mask = (const float*)d_in[1];
  const float* W    = (const float*)d_in[2];
  const float* bias = (const float*)d_in[3];

  float* out     = (float*)d_out;
  float* idx_out = out + (size_t)NROWS * ODIM;

  char*   ws       = (char*)d_ws;
  char*   WpB      = ws;
  double* partials = (double*)(ws + 262144);
  int*    counts   = (int*)(ws + 278528);
  int*    offsets  = (int*)(ws + 279552);

  convert_w_kernel<<<32, 256, 0, stream>>>(W, WpB);
  gemm_kernel<<<2048, 256, 0, stream>>>(x, WpB, bias, out, partials);
  count_kernel<<<256, 256, 0, stream>>>(mask, partials, counts, idx_out);
  scan_kernel<<<1, 256, 0, stream>>>(counts, offsets);
  scatter_kernel<<<256, 256, 0, stream>>>(mask, partials, offsets, idx_out);
}